// Round 9
// baseline (89.701 us; speedup 1.0000x reference)
//
#include <hip/hip_runtime.h>

typedef _Float16 half8  __attribute__((ext_vector_type(8)));
typedef _Float16 half4_t __attribute__((ext_vector_type(4)));
typedef float    f32x4  __attribute__((ext_vector_type(4)));

#define B_SZ    64
#define S_SZ    4096
#define H_SZ    256
#define CHUNKS  8
#define SCHUNK  512
#define TILE_R  32
#define NTILES  (SCHUNK / TILE_R)   // 16
#define PAD_H   264                 // row stride 132 words

__device__ __forceinline__ float tanh_fast(float x) {
  // 1 - 2/(e^{2x}+1); rcpf: +inf -> 1, -inf -> -1, no NaN
  return 1.f - 2.f * __builtin_amdgcn_rcpf(__expf(2.f * x) + 1.f);
}

// LDS-visibility barrier that does NOT drain vmcnt: global prefetch stays in flight.
__device__ __forceinline__ void lds_barrier() {
  asm volatile("s_waitcnt lgkmcnt(0)" ::: "memory");
  __builtin_amdgcn_s_barrier();
}

// After shl8,shl4,shl2,shl1 (bound_ctrl zero-fill): lane 0 of each 16-lane row = row sum.
template<int CTRL>
__device__ __forceinline__ float dpp_add_shl(float x) {
  int s = __builtin_amdgcn_update_dpp(0, __builtin_bit_cast(int, x), CTRL, 0xf, 0xf, true);
  return x + __builtin_bit_cast(float, s);
}
__device__ __forceinline__ float row_reduce16(float x) {
  x = dpp_add_shl<0x108>(x);  // row_shl:8
  x = dpp_add_shl<0x104>(x);  // row_shl:4
  x = dpp_add_shl<0x102>(x);  // row_shl:2
  x = dpp_add_shl<0x101>(x);  // row_shl:1
  return x;
}

// ---------------- kernel 0a: bias[b][k] = sum_h final_h[b][h] * W2[k][h] ----------------
__global__ __launch_bounds__(256) void bias_kernel(const float* __restrict__ fh,
                                                   const float* __restrict__ W2,
                                                   float* __restrict__ bias) {
  const int b = blockIdx.x, k = threadIdx.x;
  __shared__ float fsh[H_SZ];
  fsh[k] = fh[b * H_SZ + k];
  __syncthreads();
  const float* wrow = W2 + (size_t)k * H_SZ;
  float s = 0.f;
#pragma unroll 4
  for (int h = 0; h < H_SZ; h += 4) {
    f32x4 w = *(const f32x4*)(wrow + h);
    s += w[0] * fsh[h] + w[1] * fsh[h + 1] + w[2] * fsh[h + 2] + w[3] * fsh[h + 3];
  }
  bias[b * H_SZ + k] = s;
}

// ---------------- kernel 0b: pack W1 into f16 fragment order -----------------------------
// id = ((wave*2 + cf)*8 + ks)*64 + lane ; half8 = W1[n][k0..k0+7],
// n = wave*32 + cf*16 + (lane&15), k0 = ks*32 + (lane>>4)*8.  (8192 half8 = 131 KB)
__global__ __launch_bounds__(512) void pack_kernel(const float* __restrict__ W1,
                                                   _Float16* __restrict__ w1p) {
  const int id = blockIdx.x * 512 + threadIdx.x;   // 0..8191
  const int l  = id & 63, ks = (id >> 6) & 7, cf = (id >> 9) & 1, w = id >> 10;
  const int n  = w * 32 + cf * 16 + (l & 15);
  const int k0 = ks * 32 + (l >> 4) * 8;
  const float* src = W1 + (size_t)n * H_SZ + k0;
  const f32x4 a = *(const f32x4*)src;
  const f32x4 c = *(const f32x4*)(src + 4);
  half8 h;
#pragma unroll
  for (int j = 0; j < 4; ++j) { h[j] = (_Float16)a[j]; h[4 + j] = (_Float16)c[j]; }
  *(half8*)(w1p + (size_t)id * 8) = h;
}

// ---------------- kernel 1: fused; cf0 W1-frags in regs, cf1 streamed from L2 ------------
// grid 512 = 64 b * 8 chunks; block 512 = 8 waves. Wave w owns proj cols [32w, 32w+32).
// Per t: stage(t)->As[t%3]; reissue ld(t+1); issue 8 w1p b128 loads; barrier;
//        MFMA+score(t)->spartT[t&1]; context(t-1).
__global__ __launch_bounds__(512, 2) void fused_kernel(const float* __restrict__ enc,
                                                       const float* __restrict__ W1,
                                                       const _Float16* __restrict__ w1p,
                                                       const float* __restrict__ v,
                                                       const float* __restrict__ bias,
                                                       float* __restrict__ pc,   // [512][256]
                                                       float* __restrict__ pl) { // [512]
  __shared__ _Float16 As[3][TILE_R][PAD_H] __attribute__((aligned(16)));  // 49.5 KB
  __shared__ float spartT[2][TILE_R][12];  // score partials, double-buffered
  __shared__ float cpart[8][H_SZ];         // epilogue context merge
  __shared__ float lArr[8];

  const int tid  = threadIdx.x;
  const int wave = tid >> 6;
  const int lane = tid & 63;
  const int nlo  = lane & 15;
  const int g    = lane >> 4;
  const int khi  = g * 8;
  const int b     = blockIdx.x >> 3;
  const int chunk = blockIdx.x & 7;
  const size_t encBase = ((size_t)b * S_SZ + (size_t)chunk * SCHUNK) * H_SZ;
  const float* src0 = enc + encBase + (size_t)tid * 4;

  // prologue: issue tile-0 loads FIRST (critical stream)
  f32x4 ld[4];
#pragma unroll
  for (int i = 0; i < 4; ++i) ld[i] = *(const f32x4*)(src0 + i * 2048);

  // ---- cf0 W1 fragments in registers (32 VGPR); cf1 streamed per tile from w1p
  half8 wf0[8];
  {
    const int n = wave * 32 + nlo;
    const float* wrow = W1 + (size_t)n * H_SZ + khi;
#pragma unroll
    for (int ks = 0; ks < 8; ++ks) {
      f32x4 w0 = *(const f32x4*)(wrow + ks * 32);
      f32x4 w1 = *(const f32x4*)(wrow + ks * 32 + 4);
      half8 h;
#pragma unroll
      for (int j = 0; j < 4; ++j) { h[j] = (_Float16)w0[j]; h[4 + j] = (_Float16)w1[j]; }
      wf0[ks] = h;
    }
  }
  // per-tile streamed base: id = ((wave*2+1)*8 + ks)*64 + lane
  const _Float16* w1base = w1p + ((size_t)((wave * 2 + 1) * 8) * 64 + lane) * 8;

  const int n0c = wave * 32 + nlo;
  const float vv0 = v[n0c],               vv1 = v[n0c + 16];
  const float bv0 = bias[b * H_SZ + n0c], bv1 = bias[b * H_SZ + n0c + 16];

  float l_acc = 0.f;
  float c0 = 0.f, c1 = 0.f, c2 = 0.f, c3 = 0.f;  // context h-slice: h = 4*lane..+3

  int p = 0;        // t % 3
  int pm1 = 2;      // (t-1) % 3

#pragma unroll 1
  for (int t = 0; t < NTILES; ++t) {
    // stage(t): consume ld -> As[p]; reissue for t+1
#pragma unroll
    for (int i = 0; i < 4; ++i) {
      const int f4 = tid + i * 512;
      const int r = f4 >> 6, hq = (f4 & 63) * 4;
      half4_t hv;
      hv[0] = (_Float16)ld[i][0]; hv[1] = (_Float16)ld[i][1];
      hv[2] = (_Float16)ld[i][2]; hv[3] = (_Float16)ld[i][3];
      *(half4_t*)&As[p][r][hq] = hv;
    }
    if (t < NTILES - 1) {
      const float* srcN = src0 + (size_t)(t + 1) * TILE_R * H_SZ;
#pragma unroll
      for (int i = 0; i < 4; ++i) ld[i] = *(const f32x4*)(srcN + i * 2048);
    }
    // issue cf1 W1-frag loads for this tile (L2-resident; land during barrier + d0 chain)
    half8 w1s[8];
#pragma unroll
    for (int ks = 0; ks < 8; ++ks) w1s[ks] = *(const half8*)(w1base + (size_t)ks * 64 * 8);

    lds_barrier();   // As[p] + spartT[(t-1)&1] visible; vmem stays in flight

    // ---- MFMA+score(t): proj tile [32 x 32(this wave)] (bias in acc init)
#pragma unroll
    for (int rf = 0; rf < 2; ++rf) {
      f32x4 d0 = {bv0, bv0, bv0, bv0}, d1 = {bv1, bv1, bv1, bv1};
#pragma unroll
      for (int ks = 0; ks < 8; ++ks) {
        half8 a = *(const half8*)&As[p][rf * 16 + nlo][ks * 32 + khi];
        d0 = __builtin_amdgcn_mfma_f32_16x16x32_f16(a, wf0[ks],  d0, 0, 0, 0);
        d1 = __builtin_amdgcn_mfma_f32_16x16x32_f16(a, w1s[ks], d1, 0, 0, 0);
      }
      f32x4 s4;
#pragma unroll
      for (int i = 0; i < 4; ++i)
        s4[i] = tanh_fast(d0[i]) * vv0 + tanh_fast(d1[i]) * vv1;
#pragma unroll
      for (int i = 0; i < 4; ++i) s4[i] = row_reduce16(s4[i]);
      if (nlo == 0) {  // lanes 0,16,32,48: rows rf*16 + g*4 + i
#pragma unroll
        for (int i = 0; i < 4; ++i) spartT[t & 1][rf * 16 + g * 4 + i][wave] = s4[i];
      }
    }

    // ---- context(t-1): rows [4w, 4w+4) of As[pm1]; spartT[(t-1)&1] (1 barrier old)
    if (t > 0) {
#pragma unroll
      for (int rr = 0; rr < 4; ++rr) {
        const int r = wave * 4 + rr;
        const f32x4 q0 = *(const f32x4*)&spartT[(t - 1) & 1][r][0];  // broadcast reads
        const f32x4 q1 = *(const f32x4*)&spartT[(t - 1) & 1][r][4];
        const float u = __expf(q0[0] + q0[1] + q0[2] + q0[3] + q1[0] + q1[1] + q1[2] + q1[3]);
        l_acc += u;
        half4_t a = *(const half4_t*)&As[pm1][r][lane * 4];
        c0 += u * (float)a[0];
        c1 += u * (float)a[1];
        c2 += u * (float)a[2];
        c3 += u * (float)a[3];
      }
    }
    pm1 = p;
    p = (p == 2) ? 0 : p + 1;
  }

  // ---- drain: context(NTILES-1)
  lds_barrier();
  {
    const int tl = (NTILES - 1) & 1;
#pragma unroll
    for (int rr = 0; rr < 4; ++rr) {
      const int r = wave * 4 + rr;
      const f32x4 q0 = *(const f32x4*)&spartT[tl][r][0];
      const f32x4 q1 = *(const f32x4*)&spartT[tl][r][4];
      const float u = __expf(q0[0] + q0[1] + q0[2] + q0[3] + q1[0] + q1[1] + q1[2] + q1[3]);
      l_acc += u;
      half4_t a = *(const half4_t*)&As[pm1][r][lane * 4];
      c0 += u * (float)a[0];
      c1 += u * (float)a[1];
      c2 += u * (float)a[2];
      c3 += u * (float)a[3];
    }
  }

  // ---- epilogue: merge 8 waves
  {
    f32x4 cv; cv[0] = c0; cv[1] = c1; cv[2] = c2; cv[3] = c3;
    *(f32x4*)&cpart[wave][lane * 4] = cv;
  }
  if (lane == 0) lArr[wave] = l_acc;
  __syncthreads();
  if (tid < H_SZ) {
    float s = 0.f;
#pragma unroll
    for (int w = 0; w < 8; ++w) s += cpart[w][tid];
    pc[(size_t)blockIdx.x * H_SZ + tid] = s;
  }
  if (tid == 0) {
    float L = 0.f;
#pragma unroll
    for (int w = 0; w < 8; ++w) L += lArr[w];
    pl[blockIdx.x] = L;
  }
}

// ---------------- kernel 2: merge 8 chunk partials per batch (plain sums) ----------------
__global__ __launch_bounds__(256) void combine_kernel(const float* __restrict__ pc,
                                                      const float* __restrict__ pl,
                                                      float* __restrict__ out) {
  const int b = blockIdx.x, h = threadIdx.x;
  float L = 0.f, s = 0.f;
#pragma unroll
  for (int j = 0; j < CHUNKS; ++j) {
    L += pl[b * CHUNKS + j];
    s += pc[(size_t)(b * CHUNKS + j) * H_SZ + h];
  }
  out[b * H_SZ + h] = s / L;
}

extern "C" void kernel_launch(void* const* d_in, const int* in_sizes, int n_in,
                              void* d_out, int out_size, void* d_ws, size_t ws_size,
                              hipStream_t stream) {
  const float* enc = (const float*)d_in[0];  // [64,4096,256]
  const float* fh  = (const float*)d_in[1];  // [64,256]
  const float* W1  = (const float*)d_in[2];  // [256,256]
  const float* W2  = (const float*)d_in[3];  // [256,256]
  const float* v   = (const float*)d_in[4];  // [256]
  float* out = (float*)d_out;                // [64,256]

  // ws layout (bytes): w1p [0,131072) | bias [131072,196608) | pc [196608,720896) | pl ...
  char* wsb = (char*)d_ws;
  _Float16* w1p = (_Float16*)wsb;                      // 65536 f16
  float* bias   = (float*)(wsb + 131072);              // 64*256
  float* pc     = (float*)(wsb + 196608);              // 512*256
  float* pl     = (float*)(wsb + 720896);              // 512

  pack_kernel<<<16, 512, 0, stream>>>(W1, w1p);
  bias_kernel<<<B_SZ, H_SZ, 0, stream>>>(fh, W2, bias);
  fused_kernel<<<B_SZ * CHUNKS, 512, 0, stream>>>(enc, W1, w1p, v, bias, pc, pl);
  combine_kernel<<<B_SZ, H_SZ, 0, stream>>>(pc, pl, out);
}